// Round 7
// baseline (430.787 us; speedup 1.0000x reference)
//
#include <hip/hip_runtime.h>
#include <hip/hip_bf16.h>
#include <stdint.h>

// RaWRGCNLayer:
//   out[e] = relu( (1/(cnt[e]+1)) * sum_{w in e} sum_l rel_emb[walk_ids[w,l]] @ W_l + bias )
// Round-7 algorithm change: per-entity 576-bin HISTOGRAM + dense MFMA GEMM.
//   H[e][l*192+r] (u8 counts)  =>  out = relu(diag(1/(rowsum0(H)+1)) * (H @ P) + bias)
// - hist build: 3M u32 atomics, ~contention-free (vs round-6's 10-way-contended 1M, ~110us)
// - GEMM replaces gather's 1.5GB L2 stream + VALU bf16-unpack with MFMA on dense A.
// Fallback to the verbatim round-6 bucket pipeline if ws_size too small or NR != 192.

#define OD   256   // output dim
#define DIM  128   // input dim per step
#define LW   3     // walk length

typedef __attribute__((ext_vector_type(8))) short bf16x8;
typedef __attribute__((ext_vector_type(4))) float f32x4;

// ---------------- K0: P[lr][d] and PT[d][lr]; also zero H (gemm) or counts (fallback) ----
__global__ void k_precompP(const float* __restrict__ rel_emb, const float* __restrict__ W,
                           ushort* __restrict__ P, ushort* __restrict__ PT,
                           uint4* __restrict__ zbuf, int zn4,
                           uint32_t* __restrict__ counts, int NE, int NR) {
    // zero the big buffer (H in gemm path; none in fallback)
    for (int g = blockIdx.x * 256 + threadIdx.x; g < zn4; g += gridDim.x * 256)
        zbuf[g] = make_uint4(0u, 0u, 0u, 0u);
    if (counts)
        for (int g = blockIdx.x * 256 + threadIdx.x; g < NE; g += gridDim.x * 256)
            counts[g] = 0u;

    int lr = blockIdx.x;              // lr = l*NR + r
    int l = lr / NR, r = lr - l * NR;
    __shared__ float re[DIM];
    int t = threadIdx.x;              // 256 threads, one output dim each
    if (t < DIM) re[t] = rel_emb[r * DIM + t];
    __syncthreads();
    const float* Wl = W + (size_t)(l * DIM) * OD + t;
    float acc = 0.f;
#pragma unroll 8
    for (int k = 0; k < DIM; ++k) acc = fmaf(re[k], Wl[(size_t)k * OD], acc);
    __hip_bfloat16 h = __float2bfloat16(acc);   // RNE
    ushort hu = *(ushort*)&h;
    P[(size_t)lr * OD + t] = hu;                       // row-major (fallback gather)
    PT[(size_t)t * (LW * NR) + lr] = hu;               // transposed (gemm B)
}

// ---------------- K1g: histogram — 3 near-contention-free u32 atomics per walk ----------
__global__ void k_hist(const int* __restrict__ seg, const int* __restrict__ wid,
                       uint32_t* __restrict__ H, int NW, int NR) {
    int w = blockIdx.x * blockDim.x + threadIdx.x;
    if (w >= NW) return;
    int e = seg[w];
    uint32_t base = (uint32_t)e * (uint32_t)((LW * NR) >> 2);
    int b = w * LW;
#pragma unroll
    for (int l = 0; l < LW; ++l) {
        int bin = l * NR + wid[b + l];
        atomicAdd(&H[base + (bin >> 2)], 1u << ((bin & 3) * 8));
    }
}

// ---------------- K2g: GEMM out[128xM-tile][256] = relu(inv * (H @ P) + bias) ------------
// Fixed geometry (NR==192): K=576, 3 phases of 192; per block 4 waves x (32 rows x 256 cols).
__global__ __launch_bounds__(256, 1) void k_gemm(const uint8_t* __restrict__ H8,
                                                 const ushort* __restrict__ PT,
                                                 const float* __restrict__ bias,
                                                 float* __restrict__ out, int NE) {
    __shared__ ushort Bs[256 * 200];   // [col][192 k + 8 pad] bf16  (102400 B)
    __shared__ ushort As[128 * 72];    // [row][64 k bf16 + 8 pad]   (18432 B)
    __shared__ int rowsum[128];
    const int t = threadIdx.x;
    const int w = t >> 6;              // wave 0..3 -> rows w*32..w*32+31
    const int l = t & 63;
    const int lq = l >> 4;             // lane quarter
    const int l16 = l & 15;
    const int m0 = blockIdx.x * 128;

    f32x4 acc[2][16];
#pragma unroll
    for (int mf = 0; mf < 2; ++mf)
#pragma unroll
        for (int nf = 0; nf < 16; ++nf) acc[mf][nf] = (f32x4){0.f, 0.f, 0.f, 0.f};
    if (t < 128) rowsum[t] = 0;

    for (int p = 0; p < 3; ++p) {
        // ---- stage Bs = PT[:, p*192 .. p*192+192)  (cols x k, bf16) ----
        for (int it = 0; it < 24; ++it) {
            int id = t + 256 * it;              // 0..6143
            int col = id / 24, c16 = id % 24;   // c16: 8-bf16 chunk within the 192-k slice
            uint4 v = *(const uint4*)(PT + (size_t)col * 576 + p * 192 + c16 * 8);
            *(uint4*)&Bs[col * 200 + c16 * 8] = v;
        }
        __syncthreads();                         // Bs ready; rowsum zero visible (p==0)

        for (int c = 0; c < 3; ++c) {            // 64-k chunks within the phase
            // ---- stage As: 128 rows x 64 u8 -> bf16 (+ rowsum during phase 0) ----
#pragma unroll
            for (int it = 0; it < 2; ++it) {
                int id = t + 256 * it;           // 0..511
                int row = id >> 2, c16 = id & 3;
                uint4 v = *(const uint4*)(H8 + (size_t)(m0 + row) * 576 + p * 192 + c * 64 + c16 * 16);
                uint32_t wds[4] = {v.x, v.y, v.z, v.w};
                ushort hs[16];
                int s = 0;
#pragma unroll
                for (int q = 0; q < 4; ++q) {
                    uint32_t u = wds[q];
#pragma unroll
                    for (int bb = 0; bb < 4; ++bb) {
                        uint32_t byv = (u >> (8 * bb)) & 255u;
                        s += (int)byv;
                        __hip_bfloat16 h = __float2bfloat16((float)byv);  // exact (<=255)
                        hs[q * 4 + bb] = *(ushort*)&h;
                    }
                }
                if (p == 0) atomicAdd(&rowsum[row], s);
                ushort* dst = &As[row * 72 + c16 * 16];
                *(uint4*)(dst) = *(uint4*)&hs[0];
                *(uint4*)(dst + 8) = *(uint4*)&hs[8];
            }
            __syncthreads();                     // As ready

#pragma unroll
            for (int s2 = 0; s2 < 2; ++s2) {     // two 32-k MFMA substeps
                bf16x8 a0 = *(const bf16x8*)&As[(w * 32 + l16) * 72 + s2 * 32 + lq * 8];
                bf16x8 a1 = *(const bf16x8*)&As[(w * 32 + 16 + l16) * 72 + s2 * 32 + lq * 8];
#pragma unroll
                for (int nf = 0; nf < 16; ++nf) {
                    bf16x8 b = *(const bf16x8*)&Bs[(nf * 16 + l16) * 200 + c * 64 + s2 * 32 + lq * 8];
                    acc[0][nf] = __builtin_amdgcn_mfma_f32_16x16x32_bf16(a0, b, acc[0][nf], 0, 0, 0);
                    acc[1][nf] = __builtin_amdgcn_mfma_f32_16x16x32_bf16(a1, b, acc[1][nf], 0, 0, 0);
                }
            }
            __syncthreads();                     // done reading As before restage
        }
    }

    // ---- epilogue: inv from rowsum (cnt = level-0 row-sum), bias, relu, f32 store ----
    const int wrow = w * 32;
#pragma unroll
    for (int mf = 0; mf < 2; ++mf) {
        float inv[4];
#pragma unroll
        for (int i = 0; i < 4; ++i)
            inv[i] = 1.f / (float)(rowsum[wrow + mf * 16 + lq * 4 + i] + 1);
#pragma unroll
        for (int nf = 0; nf < 16; ++nf) {
            int col = nf * 16 + l16;
            float bb = bias[col];
#pragma unroll
            for (int i = 0; i < 4; ++i) {
                int grow = m0 + wrow + mf * 16 + lq * 4 + i;
                if (grow < NE) {
                    float v = fmaxf(fmaf(acc[mf][nf][i], inv[i], bb), 0.f);
                    out[(size_t)grow * OD + col] = v;
                }
            }
        }
    }
}

// ================= fallback: verbatim round-6 bucket pipeline =================
__global__ void k_fill(const int* __restrict__ seg, const int* __restrict__ wid,
                       uint32_t* __restrict__ counts, uint32_t* __restrict__ csr,
                       int NW, int SLOT) {
    int w = blockIdx.x * blockDim.x + threadIdx.x;
    if (w >= NW) return;
    int s = seg[w];
    uint32_t r = atomicAdd(&counts[s], 1u);
    if (r < (uint32_t)SLOT) {
        int b = w * LW;
        uint32_t r0 = (uint32_t)wid[b], r1 = (uint32_t)wid[b + 1], r2 = (uint32_t)wid[b + 2];
        csr[(size_t)s * SLOT + r] = r0 | (r1 << 8) | (r2 << 16);
    }
}

__device__ __forceinline__ void acc8(float* acc, uint4 q) {
    acc[0] += __uint_as_float(q.x << 16);
    acc[1] += __uint_as_float(q.x & 0xffff0000u);
    acc[2] += __uint_as_float(q.y << 16);
    acc[3] += __uint_as_float(q.y & 0xffff0000u);
    acc[4] += __uint_as_float(q.z << 16);
    acc[5] += __uint_as_float(q.z & 0xffff0000u);
    acc[6] += __uint_as_float(q.w << 16);
    acc[7] += __uint_as_float(q.w & 0xffff0000u);
}

__global__ __launch_bounds__(256) void k_gather(const uint32_t* __restrict__ counts,
                                                const uint32_t* __restrict__ csr,
                                                const ushort* __restrict__ P,
                                                const float* __restrict__ bias,
                                                float* __restrict__ out,
                                                int NR, int NE, int SLOT) {
    int wave = threadIdx.x >> 6;
    int lane = threadIdx.x & 63;
    int e = blockIdx.x * 4 + wave;
    if (e >= NE) return;
    int half = lane >> 5;
    int c = lane & 31;
    const char* Pb = (const char*)P;
    const uint32_t NR1 = (uint32_t)NR * 512u;
    const uint32_t NR2 = 2u * (uint32_t)NR * 512u;
    uint32_t cnt = counts[e];
    uint32_t n = cnt > (uint32_t)SLOT ? (uint32_t)SLOT : cnt;
    const uint32_t* wl = csr + (size_t)e * SLOT;
    uint32_t laneByte = (uint32_t)c * 16u;
    float acc[8] = {0.f, 0.f, 0.f, 0.f, 0.f, 0.f, 0.f, 0.f};

    uint32_t i = 0;
    for (; i + 2 <= n; i += 2) {
        uint32_t p0 = wl[i], p1 = wl[i + 1];
        uint32_t A0 = (p0 & 255u) * 512u;
        uint32_t A1 = ((p0 >> 8) & 255u) * 512u + NR1;
        uint32_t A2 = ((p0 >> 16) & 255u) * 512u + NR2;
        uint32_t B0 = (p1 & 255u) * 512u;
        uint32_t B1 = ((p1 >> 8) & 255u) * 512u + NR1;
        uint32_t B2 = ((p1 >> 16) & 255u) * 512u + NR2;
        uint32_t o0 = half ? A1 : A0;
        uint32_t o1 = half ? B0 : A2;
        uint32_t o2 = half ? B2 : B1;
        uint4 q0 = *(const uint4*)(Pb + o0 + laneByte);
        uint4 q1 = *(const uint4*)(Pb + o1 + laneByte);
        uint4 q2 = *(const uint4*)(Pb + o2 + laneByte);
        acc8(acc, q0);
        acc8(acc, q1);
        acc8(acc, q2);
    }
    if (i < n) {
        uint32_t p0 = wl[i];
        uint32_t A0 = (p0 & 255u) * 512u;
        uint32_t A1 = ((p0 >> 8) & 255u) * 512u + NR1;
        uint32_t A2 = ((p0 >> 16) & 255u) * 512u + NR2;
        uint32_t o0 = half ? A1 : A0;
        uint4 q0 = *(const uint4*)(Pb + o0 + laneByte);
        acc8(acc, q0);
        if (!half) {
            uint4 q1 = *(const uint4*)(Pb + A2 + laneByte);
            acc8(acc, q1);
        }
    }

#pragma unroll
    for (int k = 0; k < 8; ++k) acc[k] += __shfl_xor(acc[k], 32);

    float inv = 1.f / (float)(cnt + 1u);
    int f4 = c * 2 + half;
    float4 bb = ((const float4*)bias)[f4];
    int ab = half * 4;
    float4 o;
    o.x = fmaxf(fmaf(acc[ab + 0], inv, bb.x), 0.f);
    o.y = fmaxf(fmaf(acc[ab + 1], inv, bb.y), 0.f);
    o.z = fmaxf(fmaf(acc[ab + 2], inv, bb.z), 0.f);
    o.w = fmaxf(fmaf(acc[ab + 3], inv, bb.w), 0.f);
    ((float4*)out)[(size_t)e * 64 + f4] = o;
}

extern "C" void kernel_launch(void* const* d_in, const int* in_sizes, int n_in,
                              void* d_out, int out_size, void* d_ws, size_t ws_size,
                              hipStream_t stream) {
    const int*   seg     = (const int*)d_in[1];
    const int*   wid     = (const int*)d_in[2];
    const float* rel_emb = (const float*)d_in[3];
    const float* weight  = (const float*)d_in[4];
    const float* bias    = (const float*)d_in[5];
    float*       out     = (float*)d_out;

    const int NE = out_size / OD;            // 100000
    const int NW = in_sizes[1];              // 1000000
    const int NR = in_sizes[3] / DIM;        // 192
    const int K  = LW * NR;                  // 576

    char* ws = (char*)d_ws;
    size_t o = 0;
    auto alloc = [&](size_t bytes) { void* p = ws + o; o += (bytes + 15) & ~(size_t)15; return p; };
    ushort* P  = (ushort*)alloc((size_t)K * OD * sizeof(ushort));   // 294,912 B
    ushort* PT = (ushort*)alloc((size_t)OD * K * sizeof(ushort));   // 294,912 B
    (void)n_in;

    const int NEpad = ((NE + 127) / 128) * 128;
    const size_t Hbytes = (size_t)NEpad * K;                        // 57,655,296 B
    const bool gemm_ok = (NR == 192) && (ws_size >= o + Hbytes + 64);

    if (gemm_ok) {
        uint8_t* H = (uint8_t*)alloc(Hbytes);
        int zn4 = (int)(Hbytes / 16);
        k_precompP<<<K, 256, 0, stream>>>(rel_emb, weight, P, PT,
                                          (uint4*)H, zn4, nullptr, NE, NR);
        k_hist    <<<(NW + 255) / 256, 256, 0, stream>>>(seg, wid, (uint32_t*)H, NW, NR);
        k_gemm    <<<NEpad / 128, 256, 0, stream>>>(H, PT, bias, out, NE);
    } else {
        // verbatim round-6 pipeline
        uint32_t* counts = (uint32_t*)alloc((size_t)NE * 4);
        size_t avail = (ws_size > o) ? (ws_size - o) : 0;
        int SLOT = (int)(avail / ((size_t)NE * 4));
        if (SLOT > 40) SLOT = 40;
        if (SLOT < 1) SLOT = 1;
        uint32_t* csr = (uint32_t*)alloc((size_t)NE * SLOT * 4);
        k_precompP<<<K, 256, 0, stream>>>(rel_emb, weight, P, PT,
                                          (uint4*)nullptr, 0, counts, NE, NR);
        k_fill    <<<(NW + 255) / 256, 256, 0, stream>>>(seg, wid, counts, csr, NW, SLOT);
        k_gather  <<<(NE + 3) / 4, 256, 0, stream>>>(counts, csr, P, bias, out, NR, NE, SLOT);
    }
}

// Round 8
// 294.536 us; speedup vs baseline: 1.4626x; 1.4626x over previous
//
#include <hip/hip_runtime.h>
#include <hip/hip_bf16.h>
#include <stdint.h>

// RaWRGCNLayer via histogram + MFMA GEMM, ZERO device-scope atomics.
//   P[k][d] = (rel_emb @ W_l) precomputed bf16; H[e][576] u8 built by bucket pipeline:
//   count (LDS hist, private rows) -> scan (1 block) -> scatter (LDS cursors) ->
//   histb (per-128-entity LDS slab) -> gemm (128x256 tile, 2 blocks/CU, 12 ds : 32 MFMA).
// Fallback (ws too small): round-7 global-atomic hist + the new gemm.

#define OD   256
#define DIM  128
#define LW   3
#define NRR  192          // 2*num_relations
#define KK   576          // LW*NRR
#define KW   144          // KK/4 u32 words per entity row
#define NBLK 256          // blocks in count/scatter passes
#define BROW 128          // entities per bucket / per gemm M-tile

typedef __attribute__((ext_vector_type(8))) short bf16x8;
typedef __attribute__((ext_vector_type(4))) float f32x4;

// ---------- K0: PTS (staged-order P^T, bf16) + optional zero of H (fallback) ----------
__global__ void k_precomp(const float* __restrict__ rel_emb, const float* __restrict__ W,
                          ushort* __restrict__ PTS, uint4* __restrict__ zbuf, int zn4) {
    if (zbuf)
        for (int g = blockIdx.x * 256 + threadIdx.x; g < zn4; g += gridDim.x * 256)
            zbuf[g] = make_uint4(0u, 0u, 0u, 0u);
    int lr = blockIdx.x;                 // k index 0..575
    int l = lr / NRR, r = lr - l * NRR;
    __shared__ float re[DIM];
    int t = threadIdx.x;                 // output dim 0..255
    if (t < DIM) re[t] = rel_emb[r * DIM + t];
    __syncthreads();
    const float* Wl = W + (size_t)(l * DIM) * OD + t;
    float acc = 0.f;
#pragma unroll 8
    for (int k = 0; k < DIM; ++k) acc = fmaf(re[k], Wl[(size_t)k * OD], acc);
    __hip_bfloat16 h = __float2bfloat16(acc);
    ushort hu = *(ushort*)&h;
    // PTS[( (chunk*256 + d )*64 + j*8 + jj ] = P^T[d][k],  k = chunk*64 + j*8 + jj
    int chunk = lr >> 6, j = (lr & 63) >> 3, jj = lr & 7;
    PTS[((size_t)(chunk * 256 + t)) * 64 + j * 8 + jj] = hu;
}

// ---------- K1: per-block LDS bucket counts -> private global rows (no atomics) -------
__global__ __launch_bounds__(256) void k_count(const int* __restrict__ seg,
                                               uint32_t* __restrict__ cntG,
                                               int NW, int NBK, int CH) {
    __shared__ uint32_t h[1024];
    int t = threadIdx.x, blk = blockIdx.x;
    for (int i = t; i < NBK; i += 256) h[i] = 0u;
    __syncthreads();
    int lo = blk * CH, hi = min(NW, lo + CH);
    for (int i = lo + t; i < hi; i += 256) atomicAdd(&h[seg[i] >> 7], 1u);  // LDS atomic
    __syncthreads();
    for (int i = t; i < NBK; i += 256) cntG[(size_t)blk * NBK + i] = h[i];
}

// ---------- K2: 2D exclusive scan: cntG[blk][bk] -> start positions; bstart[bk] -------
__global__ __launch_bounds__(1024) void k_scan(uint32_t* __restrict__ cntG,
                                               uint32_t* __restrict__ bstart,
                                               int NBK, int NW) {
    __shared__ uint32_t s[1024];
    int t = threadIdx.x;
    uint32_t run = 0;
    if (t < NBK) {
#pragma unroll 8
        for (int blk = 0; blk < NBLK; ++blk) {
            uint32_t c = cntG[(size_t)blk * NBK + t];
            cntG[(size_t)blk * NBK + t] = run;   // within-bucket exclusive prefix
            run += c;
        }
    }
    s[t] = run;
    __syncthreads();
    uint32_t own = run;
    for (int off = 1; off < 1024; off <<= 1) {
        uint32_t v = (t >= off) ? s[t - off] : 0u;
        __syncthreads();
        s[t] += v;
        __syncthreads();
    }
    uint32_t excl = s[t] - own;                  // bucket base
    if (t < NBK) {
#pragma unroll 8
        for (int blk = 0; blk < NBLK; ++blk) cntG[(size_t)blk * NBK + t] += excl;
        bstart[t] = excl;
    }
    if (t == 0) bstart[NBK] = (uint32_t)NW;
}

// ---------- K3: scatter walk records via LDS cursors (no device atomics) --------------
__global__ __launch_bounds__(256) void k_scatter(const int* __restrict__ seg,
                                                 const int* __restrict__ wid,
                                                 const uint32_t* __restrict__ cntG,
                                                 uint2* __restrict__ recs,
                                                 int NW, int NBK, int CH) {
    __shared__ uint32_t cur[1024];
    int t = threadIdx.x, blk = blockIdx.x;
    for (int i = t; i < NBK; i += 256) cur[i] = cntG[(size_t)blk * NBK + i];
    __syncthreads();
    int lo = blk * CH, hi = min(NW, lo + CH);
    for (int i = lo + t; i < hi; i += 256) {
        int e = seg[i];
        uint32_t pos = atomicAdd(&cur[e >> 7], 1u);     // LDS atomic
        int b = i * LW;
        uint32_t pk = (uint32_t)wid[b] | ((uint32_t)wid[b + 1] << 8) | ((uint32_t)wid[b + 2] << 16);
        recs[pos] = make_uint2((uint32_t)e, pk);
    }
}

// ---------- K3b: per-bucket LDS histogram slab -> H (coalesced write) -----------------
__global__ __launch_bounds__(256) void k_histb(const uint2* __restrict__ recs,
                                               const uint32_t* __restrict__ bstart,
                                               uint32_t* __restrict__ H32) {
    __shared__ uint32_t slab[BROW * KW];         // 73,728 B, u8 counts packed in u32
    int t = threadIdx.x, b = blockIdx.x;
    for (int i = t; i < BROW * KW; i += 256) slab[i] = 0u;
    __syncthreads();
    uint32_t lo = bstart[b], hi = bstart[b + 1];
    for (uint32_t i = lo + t; i < hi; i += 256) {
        uint2 rc = recs[i];
        uint32_t base = (rc.x & (BROW - 1)) * KW;
        uint32_t pk = rc.y;
#pragma unroll
        for (int l = 0; l < LW; ++l) {
            uint32_t bin = (uint32_t)(l * NRR) + ((pk >> (8 * l)) & 255u);
            atomicAdd(&slab[base + (bin >> 2)], 1u << ((bin & 3) * 8));   // LDS atomic
        }
    }
    __syncthreads();
    uint4* dst = (uint4*)(H32 + (size_t)b * (BROW * KW));
    const uint4* s4 = (const uint4*)slab;
    for (int i = t; i < BROW * KW / 4; i += 256) dst[i] = s4[i];
}

// ---------- K4: GEMM out = relu(diag(inv) * (H @ P) + bias) ---------------------------
// 128 rows x 256 cols per block; 4 waves as 2(m)x2(n), each 64x128 (4 A x 8 B frags).
__global__ __launch_bounds__(256, 2) void k_gemm(const uint32_t* __restrict__ H32,
                                                 const ushort* __restrict__ PTS,
                                                 const float* __restrict__ bias,
                                                 float* __restrict__ out, int NE) {
    __shared__ ushort Bs[256 * 72];              // 36,864 B  [col][64k + 8 pad]
    __shared__ ushort As[128 * 72];              // 18,432 B  [row][64k + 8 pad]
    __shared__ float  inv[128];
    __shared__ uint32_t sump[256];
    const int t = threadIdx.x;
    const int w = t >> 6, l = t & 63, lq = l >> 4, l16 = l & 15;
    const int wm = w >> 1, wn = w & 1;
    const int m0 = blockIdx.x * BROW;

    // phase 0: cnt from level-0 byte sums (byte lanes bounded by cnt <= 255: no overflow)
    {
        int row = t >> 1, hf = t & 1;
        const uint32_t* hr = H32 + (size_t)(m0 + row) * KW + hf * 24;
        uint32_t sacc = 0;
#pragma unroll
        for (int q = 0; q < 24; ++q) sacc += hr[q];
        sump[t] = (sacc & 255u) + ((sacc >> 8) & 255u) + ((sacc >> 16) & 255u) + (sacc >> 24);
    }
    __syncthreads();
    if (t < 128) inv[t] = 1.f / (float)(sump[2 * t] + sump[2 * t + 1] + 1u);

    f32x4 acc[4][8];
#pragma unroll
    for (int mf = 0; mf < 4; ++mf)
#pragma unroll
        for (int nf = 0; nf < 8; ++nf) acc[mf][nf] = (f32x4){0.f, 0.f, 0.f, 0.f};

    for (int c = 0; c < 9; ++c) {
        __syncthreads();                         // previous reads done before restage
        // stage Bs from PTS (coalesced): uint4 g = c*2048 + j*256 + t
        {
            const uint4* src = (const uint4*)PTS + (size_t)c * 2048;
#pragma unroll
            for (int j = 0; j < 8; ++j) {
                int g = j * 256 + t;
                uint4 v = src[g];
                int col = g >> 3, ko8 = g & 7;
                *(uint4*)&Bs[col * 72 + ko8 * 8] = v;
            }
        }
        // stage As: u8 -> bf16 (exact: counts <= 255)
        {
            int row = t >> 1, hf = t & 1;
            const uint4* src = (const uint4*)(H32 + (size_t)(m0 + row) * KW + c * 16 + hf * 8);
            uint4 v0 = src[0], v1 = src[1];
            uint32_t wsv[8] = {v0.x, v0.y, v0.z, v0.w, v1.x, v1.y, v1.z, v1.w};
            ushort hs[32];
#pragma unroll
            for (int q = 0; q < 8; ++q) {
                uint32_t u = wsv[q];
#pragma unroll
                for (int bb = 0; bb < 4; ++bb) {
                    float fv = (float)((u >> (8 * bb)) & 255u);
                    hs[q * 4 + bb] = (ushort)(__float_as_uint(fv) >> 16);
                }
            }
            uint4* dst = (uint4*)&As[row * 72 + hf * 32];
            dst[0] = *(uint4*)&hs[0];
            dst[1] = *(uint4*)&hs[8];
            dst[2] = *(uint4*)&hs[16];
            dst[3] = *(uint4*)&hs[24];
        }
        __syncthreads();
#pragma unroll
        for (int s2 = 0; s2 < 2; ++s2) {
            bf16x8 a[4], b[8];
#pragma unroll
            for (int mf = 0; mf < 4; ++mf)
                a[mf] = *(const bf16x8*)&As[(wm * 64 + mf * 16 + l16) * 72 + s2 * 32 + lq * 8];
#pragma unroll
            for (int nf = 0; nf < 8; ++nf)
                b[nf] = *(const bf16x8*)&Bs[(wn * 128 + nf * 16 + l16) * 72 + s2 * 32 + lq * 8];
#pragma unroll
            for (int mf = 0; mf < 4; ++mf)
#pragma unroll
                for (int nf = 0; nf < 8; ++nf)
                    acc[mf][nf] = __builtin_amdgcn_mfma_f32_16x16x32_bf16(a[mf], b[nf], acc[mf][nf], 0, 0, 0);
        }
    }

    // epilogue (round-7-verified mapping: row = tile + mf*16 + lq*4 + i, col = nf*16 + l16)
#pragma unroll
    for (int mf = 0; mf < 4; ++mf) {
#pragma unroll
        for (int i = 0; i < 4; ++i) {
            int rl = wm * 64 + mf * 16 + lq * 4 + i;
            int grow = m0 + rl;
            if (grow < NE) {
                float iv = inv[rl];
#pragma unroll
                for (int nf = 0; nf < 8; ++nf) {
                    int col = wn * 128 + nf * 16 + l16;
                    float v = fmaxf(fmaf(acc[mf][nf][i], iv, bias[col]), 0.f);
                    out[(size_t)grow * OD + col] = v;
                }
            }
        }
    }
}

// ---------- fallback hist: global atomics (round-7 verbatim) --------------------------
__global__ void k_hist(const int* __restrict__ seg, const int* __restrict__ wid,
                       uint32_t* __restrict__ H, int NW) {
    int w = blockIdx.x * blockDim.x + threadIdx.x;
    if (w >= NW) return;
    int e = seg[w];
    uint32_t base = (uint32_t)e * (uint32_t)KW;
    int b = w * LW;
#pragma unroll
    for (int l = 0; l < LW; ++l) {
        int bin = l * NRR + wid[b + l];
        atomicAdd(&H[base + (bin >> 2)], 1u << ((bin & 3) * 8));
    }
}

extern "C" void kernel_launch(void* const* d_in, const int* in_sizes, int n_in,
                              void* d_out, int out_size, void* d_ws, size_t ws_size,
                              hipStream_t stream) {
    const int*   seg     = (const int*)d_in[1];
    const int*   wid     = (const int*)d_in[2];
    const float* rel_emb = (const float*)d_in[3];
    const float* weight  = (const float*)d_in[4];
    const float* bias    = (const float*)d_in[5];
    float*       out     = (float*)d_out;

    const int NE  = out_size / OD;               // 100000
    const int NW  = in_sizes[1];                 // 1000000
    const int NB  = (NE + BROW - 1) / BROW;      // 782 buckets / M-tiles
    const int NBK = NB;
    const int CH  = (NW + NBLK - 1) / NBLK;      // walks per count/scatter block
    (void)n_in;

    char* ws = (char*)d_ws;
    size_t o = 0;
    auto alloc = [&](size_t bytes) { void* p = ws + o; o += (bytes + 15) & ~(size_t)15; return p; };
    ushort* PTS = (ushort*)alloc((size_t)KK * OD * sizeof(ushort));      // 294,912 B
    const size_t Hbytes = (size_t)NB * BROW * KK;                        // 57,655,296 B
    uint32_t* H = (uint32_t*)alloc(Hbytes);

    size_t primary_extra = (size_t)(NBK + 1) * 4 + (size_t)NBLK * NBK * 4 + (size_t)NW * 8;
    bool primary = (NBK <= 1024) && (ws_size >= o + primary_extra + 64);

    if (primary) {
        uint32_t* bstart = (uint32_t*)alloc((size_t)(NBK + 1) * 4);
        uint32_t* cntG   = (uint32_t*)alloc((size_t)NBLK * NBK * 4);
        uint2*    recs   = (uint2*)   alloc((size_t)NW * 8);
        k_precomp<<<KK, 256, 0, stream>>>(rel_emb, weight, PTS, (uint4*)nullptr, 0);
        k_count  <<<NBLK, 256, 0, stream>>>(seg, cntG, NW, NBK, CH);
        k_scan   <<<1, 1024, 0, stream>>>(cntG, bstart, NBK, NW);
        k_scatter<<<NBLK, 256, 0, stream>>>(seg, wid, cntG, recs, NW, NBK, CH);
        k_histb  <<<NB, 256, 0, stream>>>(recs, bstart, H);
        k_gemm   <<<NB, 256, 0, stream>>>(H, PTS, bias, out, NE);
    } else {
        // fallback: zero H in k_precomp, global-atomic hist (round-7 proven), same gemm
        k_precomp<<<KK, 256, 0, stream>>>(rel_emb, weight, PTS, (uint4*)H, (int)(Hbytes / 16));
        k_hist   <<<(NW + 255) / 256, 256, 0, stream>>>(seg, wid, H, NW);
        k_gemm   <<<NB, 256, 0, stream>>>(H, PTS, bias, out, NE);
    }
}

// Round 9
// 223.394 us; speedup vs baseline: 1.9284x; 1.3185x over previous
//
#include <hip/hip_runtime.h>
#include <hip/hip_bf16.h>
#include <stdint.h>

// RaWRGCNLayer via histogram + MFMA GEMM, zero device-scope atomics.
// Pipeline: [precomp ∥ count] -> scanA -> scanB -> scatter -> histb(+inv) -> gemm.
// Round-9 changes vs round-8:
//  - serial 1-block k_scan (71us, 0.03% VALU) -> parallel scanA (782 blocks) + scanB (1 block)
//  - inv[] computed in k_histb from the LDS slab; gemm no longer re-reads H for rowsums
//  - precomp and count fused into one launch (independent work)

#define OD   256
#define DIM  128
#define LW   3
#define NRR  192          // 2*num_relations
#define KK   576          // LW*NRR
#define KW   144          // KK/4 u32 words per entity row
#define NBLK 256          // blocks in count/scatter passes
#define BROW 128          // entities per bucket / per gemm M-tile

typedef __attribute__((ext_vector_type(8))) short bf16x8;
typedef __attribute__((ext_vector_type(4))) float f32x4;

// ---------- K0: fused precomp (blocks < KK) + per-block bucket count (blocks >= KK) ----
__global__ __launch_bounds__(256) void k_pc(const float* __restrict__ rel_emb,
                                            const float* __restrict__ W,
                                            ushort* __restrict__ PTS,
                                            const int* __restrict__ seg,
                                            uint32_t* __restrict__ cntG,
                                            int NW, int NBK, int CH,
                                            uint4* __restrict__ zbuf, int zn4) {
    __shared__ uint32_t h[1024];   // count part
    __shared__ float re[DIM];      // precomp part
    int t = threadIdx.x;

    if (blockIdx.x >= KK) {        // ---- count: LDS histogram of entity>>7, private row ----
        int blk = blockIdx.x - KK;
        for (int i = t; i < NBK; i += 256) h[i] = 0u;
        __syncthreads();
        int lo = blk * CH, hi = min(NW, lo + CH);
        for (int i = lo + t; i < hi; i += 256) atomicAdd(&h[seg[i] >> 7], 1u);  // LDS atomic
        __syncthreads();
        for (int i = t; i < NBK; i += 256) cntG[(size_t)blk * NBK + i] = h[i];
        return;
    }
    // ---- precomp: P^T staged order; optional zero of H (fallback path only) ----
    if (zbuf)
        for (int g = blockIdx.x * 256 + t; g < zn4; g += KK * 256)
            zbuf[g] = make_uint4(0u, 0u, 0u, 0u);
    int lr = blockIdx.x;                 // k index 0..575
    int l = lr / NRR, r = lr - l * NRR;
    if (t < DIM) re[t] = rel_emb[r * DIM + t];
    __syncthreads();
    const float* Wl = W + (size_t)(l * DIM) * OD + t;
    float acc = 0.f;
#pragma unroll 8
    for (int k = 0; k < DIM; ++k) acc = fmaf(re[k], Wl[(size_t)k * OD], acc);
    __hip_bfloat16 hb = __float2bfloat16(acc);
    int chunk = lr >> 6, j = (lr & 63) >> 3, jj = lr & 7;
    PTS[((size_t)(chunk * 256 + t)) * 64 + j * 8 + jj] = *(ushort*)&hb;
}

// ---------- K1: per-bucket column scan over the NBLK count rows ------------------------
__global__ __launch_bounds__(256) void k_scanA(uint32_t* __restrict__ cntG,
                                               uint32_t* __restrict__ btot, int NBK) {
    __shared__ uint32_t s[256];
    int b = blockIdx.x, t = threadIdx.x;          // t indexes the count-block (NBLK==256)
    uint32_t c = cntG[(size_t)t * NBK + b];
    s[t] = c;
    __syncthreads();
    for (int off = 1; off < 256; off <<= 1) {
        uint32_t v = (t >= off) ? s[t - off] : 0u;
        __syncthreads();
        s[t] += v;
        __syncthreads();
    }
    cntG[(size_t)t * NBK + b] = s[t] - c;         // exclusive within bucket column
    if (t == 255) btot[b] = s[255];
}

// ---------- K2: exclusive scan of bucket totals -> bstart ------------------------------
__global__ __launch_bounds__(1024) void k_scanB(const uint32_t* __restrict__ btot,
                                                uint32_t* __restrict__ bstart,
                                                int NBK, int NW) {
    __shared__ uint32_t s[1024];
    int t = threadIdx.x;
    uint32_t own = (t < NBK) ? btot[t] : 0u;
    s[t] = own;
    __syncthreads();
    for (int off = 1; off < 1024; off <<= 1) {
        uint32_t v = (t >= off) ? s[t - off] : 0u;
        __syncthreads();
        s[t] += v;
        __syncthreads();
    }
    if (t < NBK) bstart[t] = s[t] - own;
    if (t == 0) bstart[NBK] = (uint32_t)NW;
}

// ---------- K3: scatter walk records via LDS cursors (bucket base added here) ----------
__global__ __launch_bounds__(256) void k_scatter(const int* __restrict__ seg,
                                                 const int* __restrict__ wid,
                                                 const uint32_t* __restrict__ cntG,
                                                 const uint32_t* __restrict__ bstart,
                                                 uint2* __restrict__ recs,
                                                 int NW, int NBK, int CH) {
    __shared__ uint32_t cur[1024];
    int t = threadIdx.x, blk = blockIdx.x;
    for (int i = t; i < NBK; i += 256) cur[i] = cntG[(size_t)blk * NBK + i] + bstart[i];
    __syncthreads();
    int lo = blk * CH, hi = min(NW, lo + CH);
    for (int i = lo + t; i < hi; i += 256) {
        int e = seg[i];
        uint32_t pos = atomicAdd(&cur[e >> 7], 1u);     // LDS atomic
        int b = i * LW;
        uint32_t pk = (uint32_t)wid[b] | ((uint32_t)wid[b + 1] << 8) | ((uint32_t)wid[b + 2] << 16);
        recs[pos] = make_uint2((uint32_t)e, pk);
    }
}

// ---------- K4: per-bucket LDS histogram slab -> H + invG ------------------------------
__global__ __launch_bounds__(256) void k_histb(const uint2* __restrict__ recs,
                                               const uint32_t* __restrict__ bstart,
                                               uint32_t* __restrict__ H32,
                                               float* __restrict__ invG) {
    __shared__ uint32_t slab[BROW * KW];         // 73,728 B, u8 counts packed in u32
    __shared__ uint32_t ps[256];
    int t = threadIdx.x, b = blockIdx.x;
    for (int i = t; i < BROW * KW; i += 256) slab[i] = 0u;
    __syncthreads();
    uint32_t lo = bstart[b], hi = bstart[b + 1];
    for (uint32_t i = lo + t; i < hi; i += 256) {
        uint2 rc = recs[i];
        uint32_t base = (rc.x & (BROW - 1)) * KW;
        uint32_t pk = rc.y;
#pragma unroll
        for (int l = 0; l < LW; ++l) {
            uint32_t bin = (uint32_t)(l * NRR) + ((pk >> (8 * l)) & 255u);
            atomicAdd(&slab[base + (bin >> 2)], 1u << ((bin & 3) * 8));   // LDS atomic
        }
    }
    __syncthreads();
    // inv from level-0 byte sums (words 0..47 of each row; lane sums <= cnt << 256)
    {
        int row = t >> 1, hf = t & 1;
        const uint32_t* sr = &slab[row * KW + hf * 24];
        uint32_t sacc = 0;
#pragma unroll
        for (int q = 0; q < 24; ++q) sacc += sr[q];
        ps[t] = (sacc & 255u) + ((sacc >> 8) & 255u) + ((sacc >> 16) & 255u) + (sacc >> 24);
    }
    __syncthreads();
    if (t < BROW) invG[(size_t)b * BROW + t] = 1.f / (float)(ps[2 * t] + ps[2 * t + 1] + 1u);
    // coalesced H write
    uint4* dst = (uint4*)(H32 + (size_t)b * (BROW * KW));
    const uint4* s4 = (const uint4*)slab;
    for (int i = t; i < BROW * KW / 4; i += 256) dst[i] = s4[i];
}

// ---------- K5: GEMM out = relu(diag(inv) * (H @ P) + bias) ---------------------------
__global__ __launch_bounds__(256, 2) void k_gemm(const uint32_t* __restrict__ H32,
                                                 const ushort* __restrict__ PTS,
                                                 const float* __restrict__ invG,
                                                 const float* __restrict__ bias,
                                                 float* __restrict__ out, int NE) {
    __shared__ ushort Bs[256 * 72];              // 36,864 B  [col][64k + 8 pad]
    __shared__ ushort As[128 * 72];              // 18,432 B  [row][64k + 8 pad]
    __shared__ float  inv[128];
    const int t = threadIdx.x;
    const int w = t >> 6, l = t & 63, lq = l >> 4, l16 = l & 15;
    const int wm = w >> 1, wn = w & 1;
    const int m0 = blockIdx.x * BROW;

    if (t < BROW) inv[t] = invG[m0 + t];

    f32x4 acc[4][8];
#pragma unroll
    for (int mf = 0; mf < 4; ++mf)
#pragma unroll
        for (int nf = 0; nf < 8; ++nf) acc[mf][nf] = (f32x4){0.f, 0.f, 0.f, 0.f};

    for (int c = 0; c < 9; ++c) {
        __syncthreads();
        {   // stage Bs (coalesced)
            const uint4* src = (const uint4*)PTS + (size_t)c * 2048;
#pragma unroll
            for (int j = 0; j < 8; ++j) {
                int g = j * 256 + t;
                uint4 v = src[g];
                int col = g >> 3, ko8 = g & 7;
                *(uint4*)&Bs[col * 72 + ko8 * 8] = v;
            }
        }
        {   // stage As: u8 -> bf16 (exact)
            int row = t >> 1, hf = t & 1;
            const uint4* src = (const uint4*)(H32 + (size_t)(m0 + row) * KW + c * 16 + hf * 8);
            uint4 v0 = src[0], v1 = src[1];
            uint32_t wsv[8] = {v0.x, v0.y, v0.z, v0.w, v1.x, v1.y, v1.z, v1.w};
            ushort hs[32];
#pragma unroll
            for (int q = 0; q < 8; ++q) {
                uint32_t u = wsv[q];
#pragma unroll
                for (int bb = 0; bb < 4; ++bb) {
                    float fv = (float)((u >> (8 * bb)) & 255u);
                    hs[q * 4 + bb] = (ushort)(__float_as_uint(fv) >> 16);
                }
            }
            uint4* dst = (uint4*)&As[row * 72 + hf * 32];
            dst[0] = *(uint4*)&hs[0];
            dst[1] = *(uint4*)&hs[8];
            dst[2] = *(uint4*)&hs[16];
            dst[3] = *(uint4*)&hs[24];
        }
        __syncthreads();
#pragma unroll
        for (int s2 = 0; s2 < 2; ++s2) {
            bf16x8 a[4], b[8];
#pragma unroll
            for (int mf = 0; mf < 4; ++mf)
                a[mf] = *(const bf16x8*)&As[(wm * 64 + mf * 16 + l16) * 72 + s2 * 32 + lq * 8];
#pragma unroll
            for (int nf = 0; nf < 8; ++nf)
                b[nf] = *(const bf16x8*)&Bs[(wn * 128 + nf * 16 + l16) * 72 + s2 * 32 + lq * 8];
#pragma unroll
            for (int mf = 0; mf < 4; ++mf)
#pragma unroll
                for (int nf = 0; nf < 8; ++nf)
                    acc[mf][nf] = __builtin_amdgcn_mfma_f32_16x16x32_bf16(a[mf], b[nf], acc[mf][nf], 0, 0, 0);
        }
    }

#pragma unroll
    for (int mf = 0; mf < 4; ++mf) {
#pragma unroll
        for (int i = 0; i < 4; ++i) {
            int rl = wm * 64 + mf * 16 + lq * 4 + i;
            int grow = m0 + rl;
            if (grow < NE) {
                float iv = inv[rl];
#pragma unroll
                for (int nf = 0; nf < 8; ++nf) {
                    int col = wn * 128 + nf * 16 + l16;
                    float v = fmaxf(fmaf(acc[mf][nf][i], iv, bias[col]), 0.f);
                    out[(size_t)grow * OD + col] = v;
                }
            }
        }
    }
}

// ---------- fallback: global-atomic hist + inv pass ------------------------------------
__global__ void k_hist(const int* __restrict__ seg, const int* __restrict__ wid,
                       uint32_t* __restrict__ H, int NW) {
    int w = blockIdx.x * blockDim.x + threadIdx.x;
    if (w >= NW) return;
    int e = seg[w];
    uint32_t base = (uint32_t)e * (uint32_t)KW;
    int b = w * LW;
#pragma unroll
    for (int l = 0; l < LW; ++l) {
        int bin = l * NRR + wid[b + l];
        atomicAdd(&H[base + (bin >> 2)], 1u << ((bin & 3) * 8));
    }
}

__global__ void k_inv(const uint32_t* __restrict__ H32, float* __restrict__ invG, int NEp) {
    int e = blockIdx.x * 256 + threadIdx.x;
    if (e >= NEp) return;
    const uint32_t* hr = H32 + (size_t)e * KW;
    uint32_t s = 0;
#pragma unroll 8
    for (int q = 0; q < 48; ++q) s += hr[q];
    uint32_t cnt = (s & 255u) + ((s >> 8) & 255u) + ((s >> 16) & 255u) + (s >> 24);
    invG[e] = 1.f / (float)(cnt + 1u);
}

extern "C" void kernel_launch(void* const* d_in, const int* in_sizes, int n_in,
                              void* d_out, int out_size, void* d_ws, size_t ws_size,
                              hipStream_t stream) {
    const int*   seg     = (const int*)d_in[1];
    const int*   wid     = (const int*)d_in[2];
    const float* rel_emb = (const float*)d_in[3];
    const float* weight  = (const float*)d_in[4];
    const float* bias    = (const float*)d_in[5];
    float*       out     = (float*)d_out;

    const int NE  = out_size / OD;               // 100000
    const int NW  = in_sizes[1];                 // 1000000
    const int NB  = (NE + BROW - 1) / BROW;      // 782 buckets / M-tiles
    const int NBK = NB;
    const int CH  = (NW + NBLK - 1) / NBLK;
    (void)n_in;

    char* ws = (char*)d_ws;
    size_t o = 0;
    auto alloc = [&](size_t bytes) { void* p = ws + o; o += (bytes + 15) & ~(size_t)15; return p; };
    ushort* PTS = (ushort*)alloc((size_t)KK * OD * sizeof(ushort));      // 294,912 B
    const size_t Hbytes = (size_t)NB * BROW * KK;                        // 57,655,296 B
    uint32_t* H   = (uint32_t*)alloc(Hbytes);
    float*   invG = (float*)  alloc((size_t)NB * BROW * 4);              // 400,384 B

    size_t primary_extra = (size_t)(NBK + 1) * 4 + (size_t)NBK * 4
                         + (size_t)NBLK * NBK * 4 + (size_t)NW * 8;
    bool primary = (NBK <= 1024) && (NBLK == 256) && (ws_size >= o + primary_extra + 64);

    if (primary) {
        uint32_t* bstart = (uint32_t*)alloc((size_t)(NBK + 1) * 4);
        uint32_t* btot   = (uint32_t*)alloc((size_t)NBK * 4);
        uint32_t* cntG   = (uint32_t*)alloc((size_t)NBLK * NBK * 4);
        uint2*    recs   = (uint2*)   alloc((size_t)NW * 8);
        k_pc     <<<KK + NBLK, 256, 0, stream>>>(rel_emb, weight, PTS, seg, cntG,
                                                 NW, NBK, CH, (uint4*)nullptr, 0);
        k_scanA  <<<NBK, 256, 0, stream>>>(cntG, btot, NBK);
        k_scanB  <<<1, 1024, 0, stream>>>(btot, bstart, NBK, NW);
        k_scatter<<<NBLK, 256, 0, stream>>>(seg, wid, cntG, bstart, recs, NW, NBK, CH);
        k_histb  <<<NB, 256, 0, stream>>>(recs, bstart, H, invG);
        k_gemm   <<<NB, 256, 0, stream>>>(H, PTS, invG, bias, out, NE);
    } else {
        k_pc  <<<KK, 256, 0, stream>>>(rel_emb, weight, PTS, seg, (uint32_t*)nullptr,
                                       NW, NBK, CH, (uint4*)H, (int)(Hbytes / 16));
        k_hist<<<(NW + 255) / 256, 256, 0, stream>>>(seg, wid, H, NW);
        k_inv <<<(NB * BROW + 255) / 256, 256, 0, stream>>>(H, invG, NB * BROW);
        k_gemm<<<NB, 256, 0, stream>>>(H, PTS, invG, bias, out, NE);
    }
}